// Round 10
// baseline (143.617 us; speedup 1.0000x reference)
//
#include <hip/hip_runtime.h>
#include <math.h>

#define Ddim 384
#define D4 96                      // Ddim/4
#define NUM_ITEMS 16384
#define NUM_CLUSTERS 256
#define MCS 128                    // MAX_CLUSTER_SIZE
#define NEG_INF_F (-1e9f)
#define NTOK 4096
#define TPB 16                     // tokens per cluster block
#define NClB (NTOK / TPB)          // 256 cluster blocks
#define NFILLB 2048                // fill blocks
#define RSTRIDE 97                 // member-row LDS stride in float4 (pad 96->97)

__device__ __forceinline__ float dot4(const float4& a, const float4& b) {
    return a.x * b.x + a.y * b.y + a.z * b.z + a.w * b.w;
}

// ---------- K0: standalone grid-strided fill ----------
__global__ __launch_bounds__(256) void hs_fill(float* __restrict__ dummy_out)
{
    const size_t base = (size_t)blockIdx.x * 256 + threadIdx.x;
    float4 z; z.x = z.y = z.z = z.w = 0.f;
    float4* o4 = reinterpret_cast<float4*>(dummy_out) + base;
    #pragma unroll 8
    for (int i = 0; i < 32; ++i)
        o4[(size_t)i * (NFILLB * 256)] = z;
}

// ---------- K1: bucket tokens by target cluster (1 block, 256 threads) ----------
__global__ __launch_bounds__(256) void hs_meta(
    const int* __restrict__ targets, const int* __restrict__ cluster_assign,
    int* __restrict__ wsI)
{
    __shared__ int cnt[NUM_CLUSTERS];
    __shared__ int scan[NUM_CLUSTERS];
    __shared__ int cur[NUM_CLUSTERS];
    const int tid = threadIdx.x;
    cnt[tid] = 0; cur[tid] = 0;
    __syncthreads();
    int tcv[NTOK / 256];
    #pragma unroll
    for (int i = 0; i < NTOK / 256; ++i) {
        const int t = i * 256 + tid;
        const int tc = cluster_assign[targets[t]];
        tcv[i] = tc;
        atomicAdd(&cnt[tc], 1);
    }
    __syncthreads();
    scan[tid] = cnt[tid];
    __syncthreads();
    for (int d = 1; d < 256; d <<= 1) {
        const int v = (tid >= d) ? scan[tid - d] : 0;
        __syncthreads();
        scan[tid] += v;
        __syncthreads();
    }
    wsI[tid] = scan[tid] - cnt[tid];
    if (tid == 255) wsI[256] = NTOK;
    __syncthreads();
    #pragma unroll
    for (int i = 0; i < NTOK / 256; ++i) {
        const int t = i * 256 + tid;
        const int tc = tcv[i];
        const int p = atomicAdd(&cur[tc], 1);
        wsI[257 + (scan[tc] - cnt[tc]) + p] = t;
    }
}

// ---------- K2: cluster logits/softmax (256 blocks x 512 thr, 8 waves) ----------
// __launch_bounds__(512, 1): min 1 block/CU = 2 waves/SIMD -> 256-VGPR budget.
// Without it the compiler targets higher occupancy, caps VGPRs (~60 measured in
// R5/R7), and REMATERIALIZES the 24 hf global loads inside every iteration —
// the inferred ~80-100 us cluster-phase cost across R5-R9.
__global__ __launch_bounds__(512, 1) void hs_cluster(
    const float* __restrict__ hidden,
    const float* __restrict__ cluster_emb,
    const float* __restrict__ item_mask,
    const int*   __restrict__ targets,
    const int*   __restrict__ cluster_assign,
    float* __restrict__ ws)
{
    const int cb    = blockIdx.x;          // 0..255
    const int tid   = threadIdx.x;
    const int t0    = cb * TPB;
    const int lane  = tid & 63;
    const int wave  = tid >> 6;            // 0..7
    const int whalf = wave >> 2;           // cluster half
    const int wq    = wave & 3;            // token quad
    const int q     = lane >> 4;           // cluster subgroup 0..3
    const int r     = lane & 15;           // lane within 16-lane D-split

    __shared__ float clog[TPB][NUM_CLUSTERS];   // 16 KB

    const int tw = t0 + wq * 4;
    const float4* h4 = reinterpret_cast<const float4*>(hidden);
    float4 hf[4][6];
    #pragma unroll
    for (int j = 0; j < 4; ++j)
        #pragma unroll
        for (int i = 0; i < 6; ++i)
            hf[j][i] = h4[(size_t)(tw + j) * D4 + i * 16 + r];

    const float4* ce4 = reinterpret_cast<const float4*>(cluster_emb);
    #pragma unroll 2
    for (int it = 0; it < 32; ++it) {
        const int c = whalf * 128 + it * 4 + q;
        float4 ce[6];
        #pragma unroll
        for (int i = 0; i < 6; ++i) ce[i] = ce4[(size_t)c * D4 + i * 16 + r];
        float a0 = 0.f, a1 = 0.f, a2 = 0.f, a3 = 0.f;
        #pragma unroll
        for (int i = 0; i < 6; ++i) {
            a0 += dot4(ce[i], hf[0][i]);
            a1 += dot4(ce[i], hf[1][i]);
            a2 += dot4(ce[i], hf[2][i]);
            a3 += dot4(ce[i], hf[3][i]);
        }
        // fold 4 accumulators over 16 lanes: 5 shuffles total
        const bool hi8 = (r & 8) != 0;
        float u  = hi8 ? a1 : a0;
        float uS = hi8 ? a0 : a1;
        u += __shfl_xor(uS, 8);
        float w  = hi8 ? a3 : a2;
        float wS = hi8 ? a2 : a3;
        w += __shfl_xor(wS, 8);
        const bool hi4 = (r & 4) != 0;
        float zv = hi4 ? w : u;
        float zS = hi4 ? u : w;
        zv += __shfl_xor(zS, 4);
        zv += __shfl_xor(zv, 2);
        zv += __shfl_xor(zv, 1);
        if ((r & 3) == 0) {
            const int m = (r >> 2) & 3;               // class -> token {0,2,1,3}
            const int tokj = (m == 1) ? 2 : (m == 2) ? 1 : m;
            clog[wq * 4 + tokj][c] = zv;
        }
    }
    __syncthreads();   // two waves fill each token row (halves)

    // ---- softmax + argmax (first-index tiebreak): wave w -> tokens 2w, 2w+1 ----
    #pragma unroll
    for (int p = 0; p < 2; ++p) {
        const int t  = wave * 2 + p;
        const int gt = t0 + t;
        const float v0 = clog[t][lane];
        const float v1 = clog[t][lane + 64];
        const float v2 = clog[t][lane + 128];
        const float v3 = clog[t][lane + 192];
        float bv = v0; int bi = lane;
        if (v1 > bv) { bv = v1; bi = lane + 64;  }
        if (v2 > bv) { bv = v2; bi = lane + 128; }
        if (v3 > bv) { bv = v3; bi = lane + 192; }
        #pragma unroll
        for (int m = 32; m > 0; m >>= 1) {
            const float ov = __shfl_xor(bv, m);
            const int   oi = __shfl_xor(bi, m);
            if (ov > bv || (ov == bv && oi < bi)) { bv = ov; bi = oi; }
        }
        float e = expf(v0 - bv) + expf(v1 - bv) + expf(v2 - bv) + expf(v3 - bv);
        #pragma unroll
        for (int m = 32; m > 0; m >>= 1) e += __shfl_xor(e, m);
        const float lse = bv + logf(e);
        if (lane == 0) {
            const int tc = cluster_assign[targets[gt]];
            ws[NTOK + gt]     = item_mask[gt];
            ws[2 * NTOK + gt] = clog[t][tc] - lse;
            ws[4 * NTOK + gt] = (bi == tc) ? 1.f : 0.f;
        }
    }
}

// ---------- K3: member logits, bucketed by cluster (256 blocks) ----------
__global__ __launch_bounds__(256) void hs_member(
    const float* __restrict__ hidden,
    const float* __restrict__ item_emb,
    const int*   __restrict__ targets,
    const int*   __restrict__ in_cluster_id,
    const int*   __restrict__ cluster_idx,
    const int*   __restrict__ wsI,
    float* __restrict__ ws)
{
    const int c    = blockIdx.x;
    const int tid  = threadIdx.x;
    const int lane = tid & 63;
    const int wid  = tid >> 6;

    __shared__ float4 rows[64 * RSTRIDE];   // 99.3 KB, XOR-swizzled
    __shared__ int    ids[64];

    const int off  = wsI[c];
    const int cntc = wsI[c + 1] - off;
    if (cntc == 0) return;

    if (tid < 64) ids[tid] = cluster_idx[c * MCS + tid];
    __syncthreads();

    const float4* ie4 = reinterpret_cast<const float4*>(item_emb);
    for (int j = tid; j < 64 * D4; j += 256) {
        const int s = j / D4, col = j % D4;
        const int id = ids[s];
        float4 v; v.x = v.y = v.z = v.w = 0.f;
        if (id >= 0) v = ie4[(size_t)id * D4 + col];
        rows[s * RSTRIDE + (col ^ ((s >> 3) & 7))] = v;
    }
    __syncthreads();

    const int  swz   = (lane >> 3) & 7;
    const bool valid = ids[lane] >= 0;
    const int* list  = wsI + 257;

    for (int i = wid * 2; i < cntc; i += 8) {
        const int tokA  = __builtin_amdgcn_readfirstlane(list[off + i]);
        const bool hasB = (i + 1) < cntc;
        const int tokB  = hasB ? __builtin_amdgcn_readfirstlane(list[off + i + 1]) : tokA;
        const float4* hA = reinterpret_cast<const float4*>(hidden + (size_t)tokA * Ddim);
        const float4* hB = reinterpret_cast<const float4*>(hidden + (size_t)tokB * Ddim);
        float accA = 0.f, accB = 0.f;
        #pragma unroll 8
        for (int k = 0; k < D4; ++k) {
            const float4 rv = rows[lane * RSTRIDE + (k ^ swz)];
            accA += dot4(rv, hA[k]);
            accB += dot4(rv, hB[k]);
        }
        const float mA = valid ? accA : NEG_INF_F;
        const float mB = valid ? accB : NEG_INF_F;
        float mxA = mA, mxB = mB;
        #pragma unroll
        for (int m = 32; m > 0; m >>= 1) {
            mxA = fmaxf(mxA, __shfl_xor(mxA, m));
            mxB = fmaxf(mxB, __shfl_xor(mxB, m));
        }
        float eA = valid ? expf(mA - mxA) : 0.f;
        float eB = valid ? expf(mB - mxB) : 0.f;
        #pragma unroll
        for (int m = 32; m > 0; m >>= 1) {
            eA += __shfl_xor(eA, m);
            eB += __shfl_xor(eB, m);
        }
        const int tpA = in_cluster_id[targets[tokA]];
        const int tpB = in_cluster_id[targets[tokB]];
        const float vA = __shfl(mA, tpA);
        const float vB = __shfl(mB, tpB);
        if (lane == 0) {
            ws[3 * NTOK + tokA] = vA - (mxA + logf(eA));
            if (hasB) ws[3 * NTOK + tokB] = vB - (mxB + logf(eB));
        }
    }
}

// ---------- K4: deterministic final reduction ----------
__global__ __launch_bounds__(1024) void hs_final(
    const float* __restrict__ ws, float* __restrict__ out)
{
    __shared__ double red[5][1024];
    const int tid = threadIdx.x;
    double a0 = 0, a1 = 0, a2 = 0, a3 = 0, a4 = 0;
    for (int i = tid; i < NTOK; i += 1024) {
        const float msk  = ws[NTOK + i];
        const float tlpc = ws[2 * NTOK + i];
        const float tlpi = ws[3 * NTOK + i];
        a0 += (double)(-(tlpc + tlpi) * msk);
        a1 += (double)msk;
        a2 += (double)tlpc;
        a3 += (double)tlpi;
        a4 += (double)ws[4 * NTOK + i];
    }
    red[0][tid] = a0; red[1][tid] = a1; red[2][tid] = a2;
    red[3][tid] = a3; red[4][tid] = a4;
    __syncthreads();
    for (int s2 = 512; s2 > 0; s2 >>= 1) {
        if (tid < s2) {
            red[0][tid] += red[0][tid + s2];
            red[1][tid] += red[1][tid + s2];
            red[2][tid] += red[2][tid + s2];
            red[3][tid] += red[3][tid + s2];
            red[4][tid] += red[4][tid + s2];
        }
        __syncthreads();
    }
    if (tid == 0) {
        out[0] = (float)(red[0][0] / (red[1][0] + 1e-8));
        out[1] = (float)(-red[2][0] / (double)NTOK);
        out[2] = (float)(-red[3][0] / (double)NTOK);
        out[3] = (float)(red[4][0] / (double)NTOK);
    }
}

extern "C" void kernel_launch(void* const* d_in, const int* in_sizes, int n_in,
                              void* d_out, int out_size, void* d_ws, size_t ws_size,
                              hipStream_t stream) {
    const float* hidden         = (const float*)d_in[0];
    const float* item_emb       = (const float*)d_in[1];
    const float* cluster_emb    = (const float*)d_in[2];
    const float* item_mask      = (const float*)d_in[3];
    const int*   targets        = (const int*)d_in[4];
    const int*   cluster_assign = (const int*)d_in[5];
    const int*   cluster_idx    = (const int*)d_in[6];
    const int*   in_cluster_id  = (const int*)d_in[7];

    float* out = (float*)d_out;
    float* ws  = (float*)d_ws;
    int*   wsI = (int*)(ws + 5 * NTOK);

    const size_t dummy_elems = (size_t)NTOK * NUM_ITEMS; // 67,108,864 zeros

    hs_fill<<<NFILLB, 256, 0, stream>>>(out);
    hs_meta<<<1, 256, 0, stream>>>(targets, cluster_assign, wsI);
    hs_cluster<<<NClB, 512, 0, stream>>>(
        hidden, cluster_emb, item_mask, targets, cluster_assign, ws);
    hs_member<<<NUM_CLUSTERS, 256, 0, stream>>>(
        hidden, item_emb, targets, in_cluster_id, cluster_idx, wsI, ws);
    hs_final<<<1, 1024, 0, stream>>>(ws, out + dummy_elems);
}

// Round 11
// 121.481 us; speedup vs baseline: 1.1822x; 1.1822x over previous
//
#include <hip/hip_runtime.h>
#include <math.h>

#define Ddim 384
#define D4 96                      // Ddim/4
#define NUM_ITEMS 16384
#define NUM_CLUSTERS 256
#define MCS 128                    // MAX_CLUSTER_SIZE
#define NEG_INF_F (-1e9f)
#define NTOK 4096
#define TPB 16                     // tokens per compute block
#define NCB (NTOK / TPB)           // 256 compute blocks
#define NFB 512                    // fill blocks

__device__ __forceinline__ float dot4(const float4& a, const float4& b) {
    return a.x * b.x + a.y * b.y + a.z * b.z + a.w * b.w;
}

// One grid, 768 blocks x 512 threads. bid%3!=2 -> fill; bid%3==2 -> compute.
// Compute block: 16 tokens. Cluster phase: 8 waves = 4 token-quads x 2
// cluster-halves (R9/R10 proven code). Then each wave finishes 2 tokens:
// cluster softmax + DIRECT member gather (slots 0..63 of cluster c are always
// valid: id = c + 256*m < 16384 iff m < 64) -> exact 64-slot softmax, no
// bucketing/meta/member kernels, no inter-dispatch serialization.
__global__ __launch_bounds__(512, 2) void hs_fused(
    const float* __restrict__ hidden,
    const float* __restrict__ item_emb,
    const float* __restrict__ cluster_emb,
    const float* __restrict__ item_mask,
    const int*   __restrict__ targets,
    const int*   __restrict__ cluster_assign,
    const int*   __restrict__ cluster_idx,
    const int*   __restrict__ in_cluster_id,
    float* __restrict__ dummy_out,
    float* __restrict__ ws)
{
    const int bid = blockIdx.x;
    const int tid = threadIdx.x;

    if (bid % 3 != 2) {
        // ---- fill: grid-strided plain stores; 512 blocks cover 268 MB ----
        const int fid = (bid / 3) * 2 + (bid % 3);          // 0..511
        float4 z; z.x = z.y = z.z = z.w = 0.f;
        float4* o4 = reinterpret_cast<float4*>(dummy_out)
                     + (size_t)fid * 512 + tid;
        #pragma unroll 8
        for (int i = 0; i < 64; ++i)
            o4[(size_t)i * (NFB * 512)] = z;                // 4 MB window/iter
        return;
    }

    const int cb    = bid / 3;             // 0..255
    const int t0    = cb * TPB;
    const int lane  = tid & 63;
    const int wave  = tid >> 6;            // 0..7
    const int whalf = wave >> 2;           // cluster half
    const int wq    = wave & 3;            // token quad
    const int q     = lane >> 4;           // cluster subgroup 0..3
    const int r     = lane & 15;           // 16-lane D-split

    __shared__ float clog[TPB][NUM_CLUSTERS];   // 16 KB
    __shared__ float mlog[TPB][64];             // 4 KB

    // ---- cluster logits: wave covers 128 clusters x 4 tokens ----
    const int tw = t0 + wq * 4;
    const float4* h4 = reinterpret_cast<const float4*>(hidden);
    float4 hf[4][6];
    #pragma unroll
    for (int j = 0; j < 4; ++j)
        #pragma unroll
        for (int i = 0; i < 6; ++i)
            hf[j][i] = h4[(size_t)(tw + j) * D4 + i * 16 + r];

    const float4* ce4 = reinterpret_cast<const float4*>(cluster_emb);
    #pragma unroll 2
    for (int it = 0; it < 32; ++it) {
        const int c = whalf * 128 + it * 4 + q;
        float4 ce[6];
        #pragma unroll
        for (int i = 0; i < 6; ++i) ce[i] = ce4[(size_t)c * D4 + i * 16 + r];
        float a0 = 0.f, a1 = 0.f, a2 = 0.f, a3 = 0.f;
        #pragma unroll
        for (int i = 0; i < 6; ++i) {
            a0 += dot4(ce[i], hf[0][i]);
            a1 += dot4(ce[i], hf[1][i]);
            a2 += dot4(ce[i], hf[2][i]);
            a3 += dot4(ce[i], hf[3][i]);
        }
        // fold 4 accumulators over 16 lanes: 5 shuffles total
        const bool hi8 = (r & 8) != 0;
        float u  = hi8 ? a1 : a0;
        float uS = hi8 ? a0 : a1;
        u += __shfl_xor(uS, 8);
        float w  = hi8 ? a3 : a2;
        float wS = hi8 ? a2 : a3;
        w += __shfl_xor(wS, 8);
        const bool hi4 = (r & 4) != 0;
        float zv = hi4 ? w : u;
        float zS = hi4 ? u : w;
        zv += __shfl_xor(zS, 4);
        zv += __shfl_xor(zv, 2);
        zv += __shfl_xor(zv, 1);
        if ((r & 3) == 0) {
            const int m = (r >> 2) & 3;               // class -> token {0,2,1,3}
            const int tokj = (m == 1) ? 2 : (m == 2) ? 1 : m;
            clog[wq * 4 + tokj][c] = zv;
        }
    }
    __syncthreads();   // two waves fill each token's clog row

    // ---- per wave: finish 2 tokens (softmax + member) ----
    const int r8 = lane & 7;
    const int g8 = lane >> 3;
    const float4* ie4 = reinterpret_cast<const float4*>(item_emb);

    #pragma unroll
    for (int p = 0; p < 2; ++p) {
        const int t  = wave * 2 + p;
        const int gt = t0 + t;
        const int tgt  = targets[gt];
        const int tc   = cluster_assign[tgt];
        const int tpos = in_cluster_id[tgt];
        const float msk = item_mask[gt];

        // cluster softmax + argmax (first-index tiebreak)
        const float v0 = clog[t][lane];
        const float v1 = clog[t][lane + 64];
        const float v2 = clog[t][lane + 128];
        const float v3 = clog[t][lane + 192];
        float bv = v0; int bi = lane;
        if (v1 > bv) { bv = v1; bi = lane + 64;  }
        if (v2 > bv) { bv = v2; bi = lane + 128; }
        if (v3 > bv) { bv = v3; bi = lane + 192; }
        #pragma unroll
        for (int m = 32; m > 0; m >>= 1) {
            const float ov = __shfl_xor(bv, m);
            const int   oi = __shfl_xor(bi, m);
            if (ov > bv || (ov == bv && oi < bi)) { bv = ov; bi = oi; }
        }
        float e = expf(v0 - bv) + expf(v1 - bv) + expf(v2 - bv) + expf(v3 - bv);
        #pragma unroll
        for (int m = 32; m > 0; m >>= 1) e += __shfl_xor(e, m);
        const float lse = bv + logf(e);
        const float tlpc = clog[t][tc] - lse;

        // ---- member: 8-lane groups, 8 rows in flight, 64 valid slots ----
        float4 hme[12];
        #pragma unroll
        for (int i = 0; i < 12; ++i)
            hme[i] = h4[(size_t)gt * D4 + i * 8 + r8];
        const int* crow = cluster_idx + (size_t)tc * MCS;
        #pragma unroll 2
        for (int it = 0; it < 8; ++it) {
            const int id = crow[it * 8 + g8];   // always >= 0 for slot < 64
            const float4* ir = ie4 + (size_t)id * D4;
            float pa = 0.f;
            #pragma unroll
            for (int i = 0; i < 12; ++i) pa += dot4(ir[i * 8 + r8], hme[i]);
            pa += __shfl_xor(pa, 1);
            pa += __shfl_xor(pa, 2);
            pa += __shfl_xor(pa, 4);
            if (r8 == 0) mlog[t][it * 8 + g8] = pa;
        }
        // wave-local softmax over 64 slots (exact: slots 64..127 are -1/masked)
        const float w0 = mlog[t][lane];
        float mx = w0;
        #pragma unroll
        for (int m = 32; m > 0; m >>= 1) mx = fmaxf(mx, __shfl_xor(mx, m));
        float e2 = expf(w0 - mx);
        #pragma unroll
        for (int m = 32; m > 0; m >>= 1) e2 += __shfl_xor(e2, m);
        const float tlpi = mlog[t][tpos] - (mx + logf(e2));

        if (lane == 0) {
            ws[NTOK + gt]     = msk;
            ws[2 * NTOK + gt] = tlpc;
            ws[3 * NTOK + gt] = tlpi;
            ws[4 * NTOK + gt] = (bi == tc) ? 1.f : 0.f;
        }
    }
}

// ---------- deterministic final reduction ----------
__global__ __launch_bounds__(1024) void hs_final(
    const float* __restrict__ ws, float* __restrict__ out)
{
    __shared__ double red[5][1024];
    const int tid = threadIdx.x;
    double a0 = 0, a1 = 0, a2 = 0, a3 = 0, a4 = 0;
    for (int i = tid; i < NTOK; i += 1024) {
        const float msk  = ws[NTOK + i];
        const float tlpc = ws[2 * NTOK + i];
        const float tlpi = ws[3 * NTOK + i];
        a0 += (double)(-(tlpc + tlpi) * msk);
        a1 += (double)msk;
        a2 += (double)tlpc;
        a3 += (double)tlpi;
        a4 += (double)ws[4 * NTOK + i];
    }
    red[0][tid] = a0; red[1][tid] = a1; red[2][tid] = a2;
    red[3][tid] = a3; red[4][tid] = a4;
    __syncthreads();
    for (int s2 = 512; s2 > 0; s2 >>= 1) {
        if (tid < s2) {
            red[0][tid] += red[0][tid + s2];
            red[1][tid] += red[1][tid + s2];
            red[2][tid] += red[2][tid + s2];
            red[3][tid] += red[3][tid + s2];
            red[4][tid] += red[4][tid + s2];
        }
        __syncthreads();
    }
    if (tid == 0) {
        out[0] = (float)(red[0][0] / (red[1][0] + 1e-8));
        out[1] = (float)(-red[2][0] / (double)NTOK);
        out[2] = (float)(-red[3][0] / (double)NTOK);
        out[3] = (float)(red[4][0] / (double)NTOK);
    }
}

extern "C" void kernel_launch(void* const* d_in, const int* in_sizes, int n_in,
                              void* d_out, int out_size, void* d_ws, size_t ws_size,
                              hipStream_t stream) {
    const float* hidden         = (const float*)d_in[0];
    const float* item_emb       = (const float*)d_in[1];
    const float* cluster_emb    = (const float*)d_in[2];
    const float* item_mask      = (const float*)d_in[3];
    const int*   targets        = (const int*)d_in[4];
    const int*   cluster_assign = (const int*)d_in[5];
    const int*   cluster_idx    = (const int*)d_in[6];
    const int*   in_cluster_id  = (const int*)d_in[7];

    float* out = (float*)d_out;
    float* ws  = (float*)d_ws;

    const size_t dummy_elems = (size_t)NTOK * NUM_ITEMS; // 67,108,864 zeros

    hs_fused<<<NFB + NCB, 512, 0, stream>>>(
        hidden, item_emb, cluster_emb, item_mask, targets,
        cluster_assign, cluster_idx, in_cluster_id, out, ws);
    hs_final<<<1, 1024, 0, stream>>>(ws, out + dummy_elems);
}